// Round 1
// baseline (236.787 us; speedup 1.0000x reference)
//
#include <hip/hip_runtime.h>
#include <hip/hip_bf16.h>

// VQ-VAE quantization forward for MI355X (gfx950).
// outputs (concat in d_out, fp32): quantized_ [16*4096*256], commitment_loss [1], perplexity [1]

typedef _Float16 half8_t __attribute__((ext_vector_type(8)));
typedef _Float16 half4_t __attribute__((ext_vector_type(4)));
typedef float f32x4 __attribute__((ext_vector_type(4)));

static constexpr int kRows = 65536;   // N*T
static constexpr int kD = 256;
static constexpr int kM = 512;
static constexpr int kBM = 64;        // rows per block in main kernel
static constexpr int kLdsStride = 260; // padded floats per row (260*4B: lane m vs m+8 share banks -> 2-way, free)

// ---------------- prep: normalize codebook rows -> fp16, bias = 0.5*||e_n||^2, zero hist/loss ----------------
__global__ void vq_prep(const float* __restrict__ emb, _Float16* __restrict__ enorm,
                        float* __restrict__ bias, unsigned int* __restrict__ hist,
                        float* __restrict__ loss) {
    const int j = blockIdx.x;       // code row, 512 blocks
    const int lane = threadIdx.x;   // 64 threads = 1 wave
    float4 v = ((const float4*)(emb + j * kD))[lane];
    float ss = v.x * v.x + v.y * v.y + v.z * v.z + v.w * v.w;
    #pragma unroll
    for (int off = 32; off > 0; off >>= 1) ss += __shfl_xor(ss, off);
    const float scale = 1.0f / (sqrtf(ss) + 1e-4f);
    if (lane == 0) bias[j] = 0.5f * ss * scale * scale;
    half4_t h;
    h[0] = (_Float16)(v.x * scale);
    h[1] = (_Float16)(v.y * scale);
    h[2] = (_Float16)(v.z * scale);
    h[3] = (_Float16)(v.w * scale);
    *(half4_t*)(enorm + j * kD + lane * 4) = h;
    if (j == 0) {
        for (int b = lane; b < kM; b += 64) hist[b] = 0u;
        if (lane == 0) loss[0] = 0.0f;
    }
}

// ---------------- main: distances via fp16 MFMA + argmax + gather + loss + histogram ----------------
__global__ __launch_bounds__(256) void vq_main(
    const float* __restrict__ x, const float* __restrict__ emb,
    const _Float16* __restrict__ enorm, const float* __restrict__ bias,
    unsigned int* __restrict__ hist, float* __restrict__ loss_accum,
    float* __restrict__ out) {
    __shared__ float xs[kBM * kLdsStride];
    __shared__ unsigned int lhist[kM];
    __shared__ int lidx[kBM];
    __shared__ float lred[4];

    const int t = threadIdx.x;
    const int row0 = blockIdx.x * kBM;

    lhist[t] = 0u;
    lhist[t + 256] = 0u;

    // stage x tile (64 rows x 256 fp32) into LDS, coalesced float4
    {
        const float4* xg = (const float4*)(x + (size_t)row0 * kD);
        #pragma unroll
        for (int i = 0; i < 16; ++i) {
            const int g = t * 4 + i * 1024;      // float index in row-major 64x256 tile
            float4 v = xg[t + i * 256];
            const int r = g >> 8, k = g & 255;
            *(float4*)&xs[r * kLdsStride + k] = v;
        }
    }
    __syncthreads();

    const int wave = t >> 6;
    const int lane = t & 63;
    const int qd = lane >> 4;    // quad 0..3
    const int ln = lane & 15;
    const int m0 = wave * 16;    // wave's local row base (rows m0..m0+15)

    // A fragments: A[m = ln][k = ko*32 + qd*8 + j], fp32->fp16
    half8_t a[8];
    {
        const float* xrow = &xs[(m0 + ln) * kLdsStride + qd * 8];
        #pragma unroll
        for (int ko = 0; ko < 8; ++ko) {
            const float* p = xrow + ko * 32;
            #pragma unroll
            for (int j = 0; j < 8; ++j) a[ko][j] = (_Float16)p[j];
        }
    }

    // argmax over 512 codes: score = x.e_norm - 0.5*||e_norm||^2
    float bv[4] = {-1e30f, -1e30f, -1e30f, -1e30f};
    int bi[4] = {0, 0, 0, 0};
    for (int nt = 0; nt < 32; ++nt) {
        const int c = nt * 16 + ln;   // B lane holds code c (B^T layout: [n][k])
        f32x4 acc = {0.f, 0.f, 0.f, 0.f};
        const half8_t* bp = (const half8_t*)(enorm + (size_t)c * kD + qd * 8);
        #pragma unroll
        for (int ko = 0; ko < 8; ++ko) {
            half8_t b = bp[ko * 4];  // stride 32 halves between k-chunks
            acc = __builtin_amdgcn_mfma_f32_16x16x32_f16(a[ko], b, acc, 0, 0, 0);
        }
        const float bb = bias[c];
        #pragma unroll
        for (int r = 0; r < 4; ++r) {
            const float s = acc[r] - bb;     // D[m][n]: n = ln (code), m = qd*4 + r (row)
            if (s > bv[r]) { bv[r] = s; bi[r] = c; }
        }
    }

    // reduce over the 16 lanes of each quad (same rows, different code subsets)
    #pragma unroll
    for (int r = 0; r < 4; ++r) {
        #pragma unroll
        for (int off = 1; off < 16; off <<= 1) {
            const float ov = __shfl_xor(bv[r], off);
            const int oi = __shfl_xor(bi[r], off);
            if (ov > bv[r] || (ov == bv[r] && oi < bi[r])) { bv[r] = ov; bi[r] = oi; }
        }
        if (ln == 0) {
            const int row = m0 + qd * 4 + r;
            lidx[row] = bi[r];
            atomicAdd(&lhist[bi[r]], 1u);
        }
    }
    __syncthreads();

    // epilogue: gather raw codebook rows, write quantized_, accumulate loss
    float lsum = 0.0f;
    {
        float* og = out + (size_t)row0 * kD;
        #pragma unroll
        for (int i = 0; i < 16; ++i) {
            const int g = t * 4 + i * 1024;
            const int r = g >> 8, k = g & 255;
            const float4 xv = *(const float4*)&xs[r * kLdsStride + k];
            const int idx = lidx[r];
            const float4 q = *(const float4*)(emb + (size_t)idx * kD + k);
            const float d0 = xv.x - q.x, d1 = xv.y - q.y, d2 = xv.z - q.z, d3 = xv.w - q.w;
            lsum += d0 * d0 + d1 * d1 + d2 * d2 + d3 * d3;
            float4 o;  // replicate reference fp32 op order: ((x + (q-x)) + q) / 2
            o.x = ((xv.x + (q.x - xv.x)) + q.x) * 0.5f;
            o.y = ((xv.y + (q.y - xv.y)) + q.y) * 0.5f;
            o.z = ((xv.z + (q.z - xv.z)) + q.z) * 0.5f;
            o.w = ((xv.w + (q.w - xv.w)) + q.w) * 0.5f;
            *(float4*)&og[g] = o;
        }
    }
    #pragma unroll
    for (int off = 32; off > 0; off >>= 1) lsum += __shfl_xor(lsum, off);
    if (lane == 0) lred[wave] = lsum;
    __syncthreads();
    if (t == 0) atomicAdd(loss_accum, lred[0] + lred[1] + lred[2] + lred[3]);

    // flush histogram (skip zero bins to cut atomics ~8x)
    const unsigned int h0 = lhist[t];
    if (h0) atomicAdd(&hist[t], h0);
    const unsigned int h1 = lhist[t + 256];
    if (h1) atomicAdd(&hist[t + 256], h1);
}

// ---------------- final: scalars ----------------
__global__ void vq_final(const unsigned int* __restrict__ hist,
                         const float* __restrict__ loss_accum,
                         float* __restrict__ out) {
    const int t = threadIdx.x;  // 256 threads
    __shared__ float sr[4];
    float s = 0.0f;
    for (int b = t; b < kM; b += 256) {
        const float p = (float)hist[b] * (1.0f / 65536.0f);
        s += p * logf(p + 1e-10f);
    }
    #pragma unroll
    for (int off = 32; off > 0; off >>= 1) s += __shfl_xor(s, off);
    if ((t & 63) == 0) sr[t >> 6] = s;
    __syncthreads();
    if (t == 0) {
        const float tot = sr[0] + sr[1] + sr[2] + sr[3];
        out[16777217] = expf(-tot);                          // perplexity
        out[16777216] = loss_accum[0] * (1.0f / 16777216.0f); // commitment loss
    }
}

extern "C" void kernel_launch(void* const* d_in, const int* in_sizes, int n_in,
                              void* d_out, int out_size, void* d_ws, size_t ws_size,
                              hipStream_t stream) {
    const float* x = (const float*)d_in[0];     // (16,4096,256) fp32
    const float* emb = (const float*)d_in[1];   // (512,256) fp32
    char* ws = (char*)d_ws;
    _Float16* enorm = (_Float16*)ws;                         // 512*256*2 = 262144 B
    float* bias = (float*)(ws + 262144);                     // 2048 B
    unsigned int* hist = (unsigned int*)(ws + 262144 + 2048); // 2048 B
    float* loss = (float*)(ws + 262144 + 4096);              // 4 B
    float* out = (float*)d_out;

    vq_prep<<<kM, 64, 0, stream>>>(emb, enorm, bias, hist, loss);
    vq_main<<<kRows / kBM, 256, 0, stream>>>(x, emb, enorm, bias, hist, loss, out);
    vq_final<<<1, 256, 0, stream>>>(hist, loss, out);
}

// Round 2
// 232.123 us; speedup vs baseline: 1.0201x; 1.0201x over previous
//
#include <hip/hip_runtime.h>
#include <hip/hip_bf16.h>

// VQ-VAE quantization forward for MI355X (gfx950).
// outputs (concat in d_out, fp32): quantized_ [16*4096*256], commitment_loss [1], perplexity [1]

typedef _Float16 half8_t __attribute__((ext_vector_type(8)));
typedef _Float16 half4_t __attribute__((ext_vector_type(4)));
typedef float f32x4 __attribute__((ext_vector_type(4)));

static constexpr int kRows = 65536;   // N*T
static constexpr int kD = 256;
static constexpr int kM = 512;
static constexpr int kBM = 64;        // rows per block in main kernel
static constexpr int kSH = 264;       // padded halves per LDS row (528 B = 132 dwords ≡ 4 mod 32 -> 2-way max, free)

// ---------------- prep: normalize codebook rows -> fp16, bias = 0.5*||e_n||^2, zero hist/loss ----------------
__global__ void vq_prep(const float* __restrict__ emb, _Float16* __restrict__ enorm,
                        float* __restrict__ bias, unsigned int* __restrict__ hist,
                        float* __restrict__ loss) {
    const int j = blockIdx.x;       // code row, 512 blocks
    const int lane = threadIdx.x;   // 64 threads = 1 wave
    float4 v = ((const float4*)(emb + j * kD))[lane];
    float ss = v.x * v.x + v.y * v.y + v.z * v.z + v.w * v.w;
    #pragma unroll
    for (int off = 32; off > 0; off >>= 1) ss += __shfl_xor(ss, off);
    const float scale = 1.0f / (sqrtf(ss) + 1e-4f);
    if (lane == 0) bias[j] = 0.5f * ss * scale * scale;
    half4_t h;
    h[0] = (_Float16)(v.x * scale);
    h[1] = (_Float16)(v.y * scale);
    h[2] = (_Float16)(v.z * scale);
    h[3] = (_Float16)(v.w * scale);
    *(half4_t*)(enorm + j * kD + lane * 4) = h;
    if (j == 0) {
        for (int b = lane; b < kM; b += 64) hist[b] = 0u;
        if (lane == 0) loss[0] = 0.0f;
    }
}

// ---------------- main: scores via fp16 MFMA + argmax + gather + loss + histogram ----------------
__global__ __launch_bounds__(256, 4) void vq_main(
    const float* __restrict__ x, const float* __restrict__ emb,
    const _Float16* __restrict__ enorm, const float* __restrict__ bias,
    unsigned int* __restrict__ hist, float* __restrict__ loss_accum,
    float* __restrict__ out) {
    __shared__ _Float16 xh[kBM * kSH];      // 33792 B, fp16 x tile
    __shared__ float lbias[kM];             // 2048 B
    __shared__ unsigned int lhist[kM];      // 2048 B
    __shared__ int lidx[kBM];
    __shared__ float lred[4];

    const int t = threadIdx.x;
    const int row0 = blockIdx.x * kBM;

    lhist[t] = 0u;
    lhist[t + 256] = 0u;
    lbias[t] = bias[t];
    lbias[t + 256] = bias[t + 256];

    // stage x tile (64 rows x 256) into LDS as fp16, coalesced float4 reads
    {
        const float4* xg = (const float4*)(x + (size_t)row0 * kD);
        #pragma unroll
        for (int i = 0; i < 16; ++i) {
            float4 v = xg[t + i * 256];
            const int g = t * 4 + i * 1024;      // float index in row-major 64x256 tile
            const int r = g >> 8, k = g & 255;
            half4_t h;
            h[0] = (_Float16)v.x; h[1] = (_Float16)v.y;
            h[2] = (_Float16)v.z; h[3] = (_Float16)v.w;
            *(half4_t*)&xh[r * kSH + k] = h;
        }
    }
    __syncthreads();

    const int wave = t >> 6;
    const int lane = t & 63;
    const int qd = lane >> 4;    // quad 0..3
    const int ln = lane & 15;
    const int m0 = wave * 16;    // wave's local row base (rows m0..m0+15)

    // A fragments: A[m = ln][k = ko*32 + qd*8 + j], straight ds_read_b128
    half8_t a[8];
    {
        const _Float16* xrow = &xh[(m0 + ln) * kSH + qd * 8];
        #pragma unroll
        for (int ko = 0; ko < 8; ++ko) a[ko] = *(const half8_t*)(xrow + ko * 32);
    }

    // argmax over 512 codes: score = x.e_norm - 0.5*||e_norm||^2 (bias folded into acc init)
    float bv[4] = {-1e30f, -1e30f, -1e30f, -1e30f};
    int bi[4] = {0, 0, 0, 0};
    #pragma unroll 2
    for (int nt = 0; nt < 32; ++nt) {
        const int c = nt * 16 + ln;   // B lane holds code c (B^T layout: [n][k])
        const float bb = lbias[c];
        f32x4 acc = {-bb, -bb, -bb, -bb};
        const half8_t* bp = (const half8_t*)(enorm + (size_t)c * kD + qd * 8);
        #pragma unroll
        for (int ko = 0; ko < 8; ++ko)
            acc = __builtin_amdgcn_mfma_f32_16x16x32_f16(a[ko], bp[ko * 4], acc, 0, 0, 0);
        #pragma unroll
        for (int r = 0; r < 4; ++r)
            if (acc[r] > bv[r]) { bv[r] = acc[r]; bi[r] = c; }   // D[m][n]: n=ln (code), m=qd*4+r
    }

    // reduce over the 16 lanes of each quad (same rows, different code subsets)
    #pragma unroll
    for (int r = 0; r < 4; ++r) {
        #pragma unroll
        for (int off = 1; off < 16; off <<= 1) {
            const float ov = __shfl_xor(bv[r], off);
            const int oi = __shfl_xor(bi[r], off);
            if (ov > bv[r] || (ov == bv[r] && oi < bi[r])) { bv[r] = ov; bi[r] = oi; }
        }
        if (ln == 0) {
            const int row = m0 + qd * 4 + r;
            lidx[row] = bi[r];
            atomicAdd(&lhist[bi[r]], 1u);
        }
    }
    __syncthreads();

    // epilogue: gather raw codebook rows, write quantized_, accumulate loss (x from fp16 LDS)
    float lsum = 0.0f;
    {
        float* og = out + (size_t)row0 * kD;
        #pragma unroll
        for (int i = 0; i < 16; ++i) {
            const int g = t * 4 + i * 1024;
            const int r = g >> 8, k = g & 255;
            const half4_t xv4 = *(const half4_t*)&xh[r * kSH + k];
            const int idx = lidx[r];
            const float4 q = *(const float4*)(emb + (size_t)idx * kD + k);
            const float x0 = (float)xv4[0], x1 = (float)xv4[1], x2 = (float)xv4[2], x3 = (float)xv4[3];
            const float d0 = x0 - q.x, d1 = x1 - q.y, d2 = x2 - q.z, d3 = x3 - q.w;
            lsum += d0 * d0 + d1 * d1 + d2 * d2 + d3 * d3;
            float4 o;  // ((x + (q-x)) + q) / 2
            o.x = ((x0 + (q.x - x0)) + q.x) * 0.5f;
            o.y = ((x1 + (q.y - x1)) + q.y) * 0.5f;
            o.z = ((x2 + (q.z - x2)) + q.z) * 0.5f;
            o.w = ((x3 + (q.w - x3)) + q.w) * 0.5f;
            *(float4*)&og[g] = o;
        }
    }
    #pragma unroll
    for (int off = 32; off > 0; off >>= 1) lsum += __shfl_xor(lsum, off);
    if (lane == 0) lred[wave] = lsum;
    __syncthreads();
    if (t == 0) atomicAdd(loss_accum, lred[0] + lred[1] + lred[2] + lred[3]);

    // flush histogram (skip zero bins to cut atomics)
    const unsigned int h0 = lhist[t];
    if (h0) atomicAdd(&hist[t], h0);
    const unsigned int h1 = lhist[t + 256];
    if (h1) atomicAdd(&hist[t + 256], h1);
}

// ---------------- final: scalars ----------------
__global__ void vq_final(const unsigned int* __restrict__ hist,
                         const float* __restrict__ loss_accum,
                         float* __restrict__ out) {
    const int t = threadIdx.x;  // 256 threads
    __shared__ float sr[4];
    float s = 0.0f;
    for (int b = t; b < kM; b += 256) {
        const float p = (float)hist[b] * (1.0f / 65536.0f);
        s += p * logf(p + 1e-10f);
    }
    #pragma unroll
    for (int off = 32; off > 0; off >>= 1) s += __shfl_xor(s, off);
    if ((t & 63) == 0) sr[t >> 6] = s;
    __syncthreads();
    if (t == 0) {
        const float tot = sr[0] + sr[1] + sr[2] + sr[3];
        out[16777217] = expf(-tot);                           // perplexity
        out[16777216] = loss_accum[0] * (1.0f / 16777216.0f); // commitment loss
    }
}

extern "C" void kernel_launch(void* const* d_in, const int* in_sizes, int n_in,
                              void* d_out, int out_size, void* d_ws, size_t ws_size,
                              hipStream_t stream) {
    const float* x = (const float*)d_in[0];     // (16,4096,256) fp32
    const float* emb = (const float*)d_in[1];   // (512,256) fp32
    char* ws = (char*)d_ws;
    _Float16* enorm = (_Float16*)ws;                          // 512*256*2 = 262144 B
    float* bias = (float*)(ws + 262144);                      // 2048 B
    unsigned int* hist = (unsigned int*)(ws + 262144 + 2048); // 2048 B
    float* loss = (float*)(ws + 262144 + 4096);               // 4 B
    float* out = (float*)d_out;

    vq_prep<<<kM, 64, 0, stream>>>(emb, enorm, bias, hist, loss);
    vq_main<<<kRows / kBM, 256, 0, stream>>>(x, emb, enorm, bias, hist, loss, out);
    vq_final<<<1, 256, 0, stream>>>(hist, loss, out);
}

// Round 3
// 142.301 us; speedup vs baseline: 1.6640x; 1.6312x over previous
//
#include <hip/hip_runtime.h>
#include <hip/hip_bf16.h>

// VQ-VAE quantization forward for MI355X (gfx950).
// outputs (concat in d_out, fp32): quantized_ [16*4096*256], commitment_loss [1], perplexity [1]

typedef _Float16 half8_t __attribute__((ext_vector_type(8)));
typedef _Float16 half4_t __attribute__((ext_vector_type(4)));
typedef float f32x4 __attribute__((ext_vector_type(4)));

static constexpr int kRows = 65536;   // N*T
static constexpr int kD = 256;
static constexpr int kM = 512;
static constexpr int kBM = 64;        // rows per block in main kernel

typedef const unsigned int __attribute__((address_space(1)))* gas_t;
typedef unsigned int __attribute__((address_space(3)))* las_t;

// ---------------- prep: normalize codebook -> fp16 in MFMA B-fragment order, bias, zero hist/loss --------
// swz layout: [group g=c>>4][ko=k>>5][lane = qd*16 + (c&15)][j = k&7], qd=(k>>3)&3
// so a wave's ds/global read at lane*16B yields B[k=ko*32+qd*8+j][n=g*16+ln] exactly as
// mfma_f32_16x16x32_f16 wants it.
__global__ void vq_prep(const float* __restrict__ emb, _Float16* __restrict__ swz,
                        float* __restrict__ bias, unsigned int* __restrict__ hist,
                        float* __restrict__ loss) {
    const int j = blockIdx.x;       // code row, 512 blocks
    const int lane = threadIdx.x;   // 64 threads = 1 wave
    float4 v = ((const float4*)(emb + j * kD))[lane];
    float ss = v.x * v.x + v.y * v.y + v.z * v.z + v.w * v.w;
    #pragma unroll
    for (int off = 32; off > 0; off >>= 1) ss += __shfl_xor(ss, off);
    const float scale = 1.0f / (sqrtf(ss) + 1e-4f);
    if (lane == 0) bias[j] = 0.5f * ss * scale * scale;
    half4_t h;
    h[0] = (_Float16)(v.x * scale);
    h[1] = (_Float16)(v.y * scale);
    h[2] = (_Float16)(v.z * scale);
    h[3] = (_Float16)(v.w * scale);
    // this lane covers k = 4*lane .. 4*lane+3 (all within one 8-half j-chunk)
    const int k0 = lane * 4;
    const int ko = k0 >> 5;
    const int qd = (k0 >> 3) & 3;
    const int jj = k0 & 7;          // 0 or 4
    const int off_h = (j >> 4) * 4096 + ko * 512 + (qd * 16 + (j & 15)) * 8 + jj;
    *(half4_t*)(swz + off_h) = h;
    if (j == 0) {
        for (int b = lane; b < kM; b += 64) hist[b] = 0u;
        if (lane == 0) loss[0] = 0.0f;
    }
}

// ---------------- main: scores via fp16 MFMA (B staged through LDS) + argmax + gather + loss + hist ------
__global__ __launch_bounds__(256, 4) void vq_main(
    const float* __restrict__ x, const float* __restrict__ emb,
    const _Float16* __restrict__ bswz, const float* __restrict__ bias,
    unsigned int* __restrict__ hist, float* __restrict__ loss_accum,
    float* __restrict__ out) {
    __shared__ _Float16 bb[64 * kD];        // 32 KB: one 64-code tile in fragment order
    __shared__ float lbias[kM];             // 2 KB
    __shared__ unsigned int lhist[kM];      // 2 KB
    __shared__ int lidx[kBM];
    __shared__ float lred[4];

    const int t = threadIdx.x;
    const int row0 = blockIdx.x * kBM;
    const int wave = t >> 6;
    const int lane = t & 63;
    const int qd = lane >> 4;    // quad 0..3
    const int ln = lane & 15;
    const int m0 = wave * 16;    // wave's local row base

    lhist[t] = 0u;
    lhist[t + 256] = 0u;
    lbias[t] = bias[t];
    lbias[t + 256] = bias[t + 256];

    // A fragments straight from global (one-time, lane-divergent rows): A[m=ln][k=qd*8+ko*32+j]
    half8_t a[8];
    {
        const float* xr = x + (size_t)(row0 + m0 + ln) * kD + qd * 8;
        #pragma unroll
        for (int ko = 0; ko < 8; ++ko) {
            const float4 v0 = *(const float4*)(xr + ko * 32);
            const float4 v1 = *(const float4*)(xr + ko * 32 + 4);
            half8_t h;
            h[0] = (_Float16)v0.x; h[1] = (_Float16)v0.y;
            h[2] = (_Float16)v0.z; h[3] = (_Float16)v0.w;
            h[4] = (_Float16)v1.x; h[5] = (_Float16)v1.y;
            h[6] = (_Float16)v1.z; h[7] = (_Float16)v1.w;
            a[ko] = h;
        }
    }

    // argmax over 512 codes in 8 tiles of 64; score = x.e_norm - 0.5*||e_norm||^2 (bias in acc init)
    float bv[4] = {-1e30f, -1e30f, -1e30f, -1e30f};
    int bi[4] = {0, 0, 0, 0};
    for (int tile = 0; tile < 8; ++tile) {
        __syncthreads();   // prior tile's reads done (also covers lhist/lbias init on iter 0)
        // stage 32 KB tile: each wave moves 8 chunks of 1 KB, coalesced, direct-to-LDS
        {
            const _Float16* src = bswz + (size_t)tile * 16384 + (size_t)(wave * 8) * 512 + lane * 8;
            _Float16* dst = bb + (wave * 8) * 512;
            #pragma unroll
            for (int i = 0; i < 8; ++i)
                __builtin_amdgcn_global_load_lds((gas_t)(const void*)(src + i * 512),
                                                 (las_t)(void*)(dst + i * 512), 16, 0, 0);
        }
        __syncthreads();
        #pragma unroll
        for (int sub = 0; sub < 4; ++sub) {
            const int c = tile * 64 + sub * 16 + ln;
            const float bbias = lbias[c];
            f32x4 acc = {-bbias, -bbias, -bbias, -bbias};
            const half8_t* bp = (const half8_t*)bb + sub * 512 + lane;
            #pragma unroll
            for (int ko = 0; ko < 8; ++ko)
                acc = __builtin_amdgcn_mfma_f32_16x16x32_f16(a[ko], bp[ko * 64], acc, 0, 0, 0);
            #pragma unroll
            for (int r = 0; r < 4; ++r)
                if (acc[r] > bv[r]) { bv[r] = acc[r]; bi[r] = c; }   // D[m][n]: n=ln, m=qd*4+r
        }
    }

    // reduce over the 16 lanes of each quad (same rows, different code subsets)
    #pragma unroll
    for (int r = 0; r < 4; ++r) {
        #pragma unroll
        for (int off = 1; off < 16; off <<= 1) {
            const float ov = __shfl_xor(bv[r], off);
            const int oi = __shfl_xor(bi[r], off);
            if (ov > bv[r] || (ov == bv[r] && oi < bi[r])) { bv[r] = ov; bi[r] = oi; }
        }
        if (ln == 0) {
            const int row = m0 + qd * 4 + r;
            lidx[row] = bi[r];
            atomicAdd(&lhist[bi[r]], 1u);
        }
    }
    __syncthreads();

    // epilogue: x re-read coalesced (L3-hot), gather raw codebook rows, write quantized_, loss
    float lsum = 0.0f;
    {
        const float* xg = x + (size_t)row0 * kD;
        float* og = out + (size_t)row0 * kD;
        #pragma unroll
        for (int i = 0; i < 16; ++i) {
            const int g = t * 4 + i * 1024;
            const int r = g >> 8;
            const float4 xv = *(const float4*)(xg + g);
            const int idx = lidx[r];
            const float4 q = *(const float4*)(emb + (size_t)idx * kD + (g & 255));
            const float d0 = xv.x - q.x, d1 = xv.y - q.y, d2 = xv.z - q.z, d3 = xv.w - q.w;
            lsum += d0 * d0 + d1 * d1 + d2 * d2 + d3 * d3;
            float4 o;  // ((x + (q-x)) + q) / 2
            o.x = ((xv.x + (q.x - xv.x)) + q.x) * 0.5f;
            o.y = ((xv.y + (q.y - xv.y)) + q.y) * 0.5f;
            o.z = ((xv.z + (q.z - xv.z)) + q.z) * 0.5f;
            o.w = ((xv.w + (q.w - xv.w)) + q.w) * 0.5f;
            *(float4*)&og[g] = o;
        }
    }
    #pragma unroll
    for (int off = 32; off > 0; off >>= 1) lsum += __shfl_xor(lsum, off);
    if (lane == 0) lred[wave] = lsum;
    __syncthreads();
    if (t == 0) atomicAdd(loss_accum, lred[0] + lred[1] + lred[2] + lred[3]);

    // flush histogram (skip zero bins)
    const unsigned int h0 = lhist[t];
    if (h0) atomicAdd(&hist[t], h0);
    const unsigned int h1 = lhist[t + 256];
    if (h1) atomicAdd(&hist[t + 256], h1);
}

// ---------------- final: scalars ----------------
__global__ void vq_final(const unsigned int* __restrict__ hist,
                         const float* __restrict__ loss_accum,
                         float* __restrict__ out) {
    const int t = threadIdx.x;  // 256 threads
    __shared__ float sr[4];
    float s = 0.0f;
    for (int b = t; b < kM; b += 256) {
        const float p = (float)hist[b] * (1.0f / 65536.0f);
        s += p * logf(p + 1e-10f);
    }
    #pragma unroll
    for (int off = 32; off > 0; off >>= 1) s += __shfl_xor(s, off);
    if ((t & 63) == 0) sr[t >> 6] = s;
    __syncthreads();
    if (t == 0) {
        const float tot = sr[0] + sr[1] + sr[2] + sr[3];
        out[16777217] = expf(-tot);                           // perplexity
        out[16777216] = loss_accum[0] * (1.0f / 16777216.0f); // commitment loss
    }
}

extern "C" void kernel_launch(void* const* d_in, const int* in_sizes, int n_in,
                              void* d_out, int out_size, void* d_ws, size_t ws_size,
                              hipStream_t stream) {
    const float* x = (const float*)d_in[0];     // (16,4096,256) fp32
    const float* emb = (const float*)d_in[1];   // (512,256) fp32
    char* ws = (char*)d_ws;
    _Float16* bswz = (_Float16*)ws;                           // 512*256*2 = 262144 B
    float* bias = (float*)(ws + 262144);                      // 2048 B
    unsigned int* hist = (unsigned int*)(ws + 262144 + 2048); // 2048 B
    float* loss = (float*)(ws + 262144 + 4096);               // 4 B
    float* out = (float*)d_out;

    vq_prep<<<kM, 64, 0, stream>>>(emb, bswz, bias, hist, loss);
    vq_main<<<kRows / kBM, 256, 0, stream>>>(x, emb, bswz, bias, hist, loss, out);
    vq_final<<<1, 256, 0, stream>>>(hist, loss, out);
}

// Round 4
// 138.606 us; speedup vs baseline: 1.7083x; 1.0267x over previous
//
#include <hip/hip_runtime.h>
#include <hip/hip_bf16.h>

// VQ-VAE quantization forward for MI355X (gfx950).
// outputs (concat in d_out, fp32): quantized_ [16*4096*256], commitment_loss [1], perplexity [1]
//
// Persistent-A design: 512 blocks x 512 threads; each block owns 128 rows.
// A-fragments (fp16) loaded once into registers; codebook visits LDS in 4 stages
// of 128 codes (64 KB, MFMA B-fragment order) via global_load_lds width=16.

typedef _Float16 half8_t __attribute__((ext_vector_type(8)));
typedef _Float16 half4_t __attribute__((ext_vector_type(4)));
typedef float f32x4 __attribute__((ext_vector_type(4)));

static constexpr int kRows = 65536;   // N*T
static constexpr int kD = 256;
static constexpr int kM = 512;
static constexpr int kBM = 128;       // rows per block

typedef const unsigned int __attribute__((address_space(1)))* gas_t;
typedef unsigned int __attribute__((address_space(3)))* las_t;

// ---------------- prep: normalize codebook -> fp16 in MFMA B-fragment order, bias, zero hist/loss --------
// swz layout (halves): [group g=c>>4][ko=k>>5][lane = qd*16 + (c&15)][j = k&7], qd=(k>>3)&3.
// A wave's read at lane*16B yields B[k=ko*32+qd*8+j][n=g*16+ln] as mfma_f32_16x16x32_f16 wants.
__global__ void vq_prep(const float* __restrict__ emb, _Float16* __restrict__ swz,
                        float* __restrict__ bias, unsigned int* __restrict__ hist,
                        float* __restrict__ loss) {
    const int j = blockIdx.x;       // code row, 512 blocks
    const int lane = threadIdx.x;   // 64 threads = 1 wave
    float4 v = ((const float4*)(emb + j * kD))[lane];
    float ss = v.x * v.x + v.y * v.y + v.z * v.z + v.w * v.w;
    #pragma unroll
    for (int off = 32; off > 0; off >>= 1) ss += __shfl_xor(ss, off);
    const float scale = 1.0f / (sqrtf(ss) + 1e-4f);
    if (lane == 0) bias[j] = 0.5f * ss * scale * scale;
    half4_t h;
    h[0] = (_Float16)(v.x * scale);
    h[1] = (_Float16)(v.y * scale);
    h[2] = (_Float16)(v.z * scale);
    h[3] = (_Float16)(v.w * scale);
    const int k0 = lane * 4;        // this lane covers k0..k0+3 (within one 8-half j-chunk)
    const int ko = k0 >> 5;
    const int qd = (k0 >> 3) & 3;
    const int jj = k0 & 7;          // 0 or 4
    const int off_h = (j >> 4) * 4096 + ko * 512 + (qd * 16 + (j & 15)) * 8 + jj;
    *(half4_t*)(swz + off_h) = h;
    if (j == 0) {
        for (int b = lane; b < kM; b += 64) hist[b] = 0u;
        if (lane == 0) loss[0] = 0.0f;
    }
}

// ---------------- main: persistent A-frags, codebook in 4 LDS stages, argmax + gather + loss + hist ------
__global__ __launch_bounds__(512, 4) void vq_main(
    const float* __restrict__ x, const float* __restrict__ emb,
    const _Float16* __restrict__ bswz, const float* __restrict__ bias,
    unsigned int* __restrict__ hist, float* __restrict__ loss_accum,
    float* __restrict__ out) {
    __shared__ _Float16 bb[128 * kD];       // 65536 B: one 128-code stage in fragment order
    __shared__ float lbias[kM];             // 2048 B
    __shared__ unsigned int lhist[kM];      // 2048 B
    __shared__ int lidx[kBM];               // 512 B
    __shared__ float lred[8];

    const int t = threadIdx.x;              // 0..511, 8 waves
    const int row0 = blockIdx.x * kBM;
    const int wave = t >> 6;
    const int lane = t & 63;
    const int qd = lane >> 4;               // quad 0..3
    const int ln = lane & 15;
    const int m0 = wave * 16;               // wave's local row base (rows m0..m0+15)

    lhist[t] = 0u;
    lbias[t] = bias[t];

    // A fragments, loaded ONCE: A[m=ln][k=ko*32+qd*8+j], fp32->fp16, resident in 32 VGPRs
    half8_t a[8];
    {
        const float* xr = x + (size_t)(row0 + m0 + ln) * kD + qd * 8;
        #pragma unroll
        for (int ko = 0; ko < 8; ++ko) {
            const float4 v0 = *(const float4*)(xr + ko * 32);
            const float4 v1 = *(const float4*)(xr + ko * 32 + 4);
            half8_t h;
            h[0] = (_Float16)v0.x; h[1] = (_Float16)v0.y;
            h[2] = (_Float16)v0.z; h[3] = (_Float16)v0.w;
            h[4] = (_Float16)v1.x; h[5] = (_Float16)v1.y;
            h[6] = (_Float16)v1.z; h[7] = (_Float16)v1.w;
            a[ko] = h;
        }
    }

    // argmax over 512 codes in 4 stages of 128; score = x.e_norm - 0.5*||e_norm||^2 (bias in acc init)
    float bv[4] = {-1e30f, -1e30f, -1e30f, -1e30f};
    int bi[4] = {0, 0, 0, 0};
    #pragma unroll 1
    for (int s = 0; s < 4; ++s) {
        __syncthreads();   // prior stage's ds_reads done (s=0: covers lhist/lbias init)
        // stage 64 KB = groups 8s..8s+7 of bswz, contiguous; 512 thr x 8 x 16 B, direct-to-LDS
        {
            const _Float16* src = bswz + (size_t)s * 32768 + t * 8;
            _Float16* dst = bb + t * 8;
            #pragma unroll
            for (int i = 0; i < 8; ++i)
                __builtin_amdgcn_global_load_lds((gas_t)(const void*)(src + i * 4096),
                                                 (las_t)(void*)(dst + i * 4096), 16, 0, 0);
        }
        __syncthreads();
        #pragma unroll
        for (int sub = 0; sub < 8; ++sub) {
            const int c = s * 128 + sub * 16 + ln;
            const float bbias = lbias[c];
            f32x4 acc = {-bbias, -bbias, -bbias, -bbias};
            const half8_t* bp = (const half8_t*)bb + sub * 512 + lane;
            #pragma unroll
            for (int ko = 0; ko < 8; ++ko)
                acc = __builtin_amdgcn_mfma_f32_16x16x32_f16(a[ko], bp[ko * 64], acc, 0, 0, 0);
            #pragma unroll
            for (int r = 0; r < 4; ++r)
                if (acc[r] > bv[r]) { bv[r] = acc[r]; bi[r] = c; }   // D[m][n]: n=ln, m=qd*4+r
        }
    }

    // reduce over the 16 lanes of each quad (same rows, different code subsets)
    #pragma unroll
    for (int r = 0; r < 4; ++r) {
        #pragma unroll
        for (int off = 1; off < 16; off <<= 1) {
            const float ov = __shfl_xor(bv[r], off);
            const int oi = __shfl_xor(bi[r], off);
            if (ov > bv[r] || (ov == bv[r] && oi < bi[r])) { bv[r] = ov; bi[r] = oi; }
        }
        if (ln == 0) {
            const int row = m0 + qd * 4 + r;
            lidx[row] = bi[r];
            atomicAdd(&lhist[bi[r]], 1u);
        }
    }
    __syncthreads();

    // epilogue: x re-read coalesced (L2/L3-hot), gather raw codebook row (whole wave shares one
    // row per iter -> coalesced 1 KB), write quantized_, accumulate loss
    float lsum = 0.0f;
    {
        const float* xg = x + (size_t)row0 * kD;
        float* og = out + (size_t)row0 * kD;
        #pragma unroll
        for (int i = 0; i < 16; ++i) {
            const int g = t * 4 + i * 2048;
            const int r = g >> 8;
            const float4 xv = *(const float4*)(xg + g);
            const int idx = lidx[r];
            const float4 q = *(const float4*)(emb + (size_t)idx * kD + (g & 255));
            const float d0 = xv.x - q.x, d1 = xv.y - q.y, d2 = xv.z - q.z, d3 = xv.w - q.w;
            lsum += d0 * d0 + d1 * d1 + d2 * d2 + d3 * d3;
            float4 o;  // ((x + (q-x)) + q) / 2
            o.x = ((xv.x + (q.x - xv.x)) + q.x) * 0.5f;
            o.y = ((xv.y + (q.y - xv.y)) + q.y) * 0.5f;
            o.z = ((xv.z + (q.z - xv.z)) + q.z) * 0.5f;
            o.w = ((xv.w + (q.w - xv.w)) + q.w) * 0.5f;
            *(float4*)&og[g] = o;
        }
    }
    #pragma unroll
    for (int off = 32; off > 0; off >>= 1) lsum += __shfl_xor(lsum, off);
    if (lane == 0) lred[wave] = lsum;
    __syncthreads();
    if (t == 0) {
        float bs = 0.f;
        #pragma unroll
        for (int w = 0; w < 8; ++w) bs += lred[w];
        atomicAdd(loss_accum, bs);
    }

    // flush histogram (skip zero bins)
    const unsigned int h0 = lhist[t];
    if (h0) atomicAdd(&hist[t], h0);
}

// ---------------- final: scalars ----------------
__global__ void vq_final(const unsigned int* __restrict__ hist,
                         const float* __restrict__ loss_accum,
                         float* __restrict__ out) {
    const int t = threadIdx.x;  // 256 threads
    __shared__ float sr[4];
    float s = 0.0f;
    for (int b = t; b < kM; b += 256) {
        const float p = (float)hist[b] * (1.0f / 65536.0f);
        s += p * logf(p + 1e-10f);
    }
    #pragma unroll
    for (int off = 32; off > 0; off >>= 1) s += __shfl_xor(s, off);
    if ((t & 63) == 0) sr[t >> 6] = s;
    __syncthreads();
    if (t == 0) {
        const float tot = sr[0] + sr[1] + sr[2] + sr[3];
        out[16777217] = expf(-tot);                           // perplexity
        out[16777216] = loss_accum[0] * (1.0f / 16777216.0f); // commitment loss
    }
}

extern "C" void kernel_launch(void* const* d_in, const int* in_sizes, int n_in,
                              void* d_out, int out_size, void* d_ws, size_t ws_size,
                              hipStream_t stream) {
    const float* x = (const float*)d_in[0];     // (16,4096,256) fp32
    const float* emb = (const float*)d_in[1];   // (512,256) fp32
    char* ws = (char*)d_ws;
    _Float16* bswz = (_Float16*)ws;                           // 512*256*2 = 262144 B
    float* bias = (float*)(ws + 262144);                      // 2048 B
    unsigned int* hist = (unsigned int*)(ws + 262144 + 2048); // 2048 B
    float* loss = (float*)(ws + 262144 + 4096);               // 4 B
    float* out = (float*)d_out;

    vq_prep<<<kM, 64, 0, stream>>>(emb, bswz, bias, hist, loss);
    vq_main<<<kRows / kBM, 512, 0, stream>>>(x, emb, bswz, bias, hist, loss, out);
    vq_final<<<1, 256, 0, stream>>>(hist, loss, out);
}